// Round 14
// baseline (120.736 us; speedup 1.0000x reference)
//
#include <hip/hip_runtime.h>

// ClusterLoss fused kernel for MI355X (gfx950).  R20.
// Model (fits R14-R19): B-stream L2 traffic is 512 MB at a delivered ~12 TB/s
// in every register-streamed variant (R14/16/17/19 all ~41-45us, MfmaUtil
// ~30%, regardless of occupancy/depth/setprio). Feeding MFMA at 100% needs
// ~30 TB/s of B -> pure-L2 ceiling (~12 TB/s, no L1 reuse for a 128 KB
// working set) pins MFMA at ~40%. R18 cut the traffic but collapsed
// residency (1 block/CU, 2 waves/SIMD) -> confounded.
// R20 = R18's traffic cut at R14-class residency:
//   - 512-thr block, 8 waves, EACH wave owns its own 32-row tile;
//   - block stages half-B (64 KB, R18-verified frag-linear layout) to LDS,
//     all waves sweep -> barrier -> restage half-1 -> sweep (running best);
//   - LDS demand at full MFMA rate: 53 B/cyc/CU < 128 ceiling; read pattern
//     measured conflict-free in R18 (SQ_LDS_BANK_CONFLICT=0);
//   - A fragments direct from global (verified), 16 regs, persist both halves;
//   - B L2 traffic 512 MB -> 64 MB; LDS 66 KB -> 2 blocks/CU = 4 waves/SIMD;
//   - grid 512 = one generation; per-wave epilogue, no atomics.
// Allocator rules (measured): 1024-thr or min-waves>=2 pins 64 VGPR + spill.
// Use (512,1). Spill tripwire = WRITE_SIZE.
// loss_n = 1 - 2 d na/nf + na^2 (fp32 scalars).

#define D 128

typedef __attribute__((ext_vector_type(4))) float floatx4;
typedef __attribute__((ext_vector_type(2))) long long llx2;

template <bool HI>
__device__ __forceinline__ unsigned int pk_fp8(float a, float b, unsigned int old) {
    return (unsigned int)__builtin_amdgcn_cvt_pk_fp8_f32(a, b, (int)old, HI);
}

__device__ __forceinline__ float key_pack(float v, unsigned int inv_k) {
    unsigned int u = __builtin_bit_cast(unsigned int, v);
    unsigned int r = (0x3FFu & inv_k) | (~0x3FFu & u);   // v_bfi_b32
    return __builtin_bit_cast(float, r);
}

// ---- Prep: normalize centers -> fp8 into frag-linear order (R18-verified) ----
// fragment (g, flane, kk) at (g*2 + (kk>>1))*1024 + flane*16 + (kk&1)*8;
// half h occupies bytes [h*65536, h*65536+65536).
__global__ void prep_centers(const float* __restrict__ centers,
                             unsigned char* __restrict__ bws2,
                             float* __restrict__ cnorm) {
    const int k = blockIdx.x;
    const int t = threadIdx.x;            // 128 threads, one per dim
    float v = centers[(size_t)k * D + t];
    float s = v * v;
    #pragma unroll
    for (int m = 1; m <= 32; m <<= 1) s += __shfl_xor(s, m);
    __shared__ float ws2[2];
    if ((t & 63) == 0) ws2[t >> 6] = s;
    __syncthreads();
    float total = ws2[0] + ws2[1];
    float n = sqrtf(total);
    float q = v / fmaxf(n, 1e-12f);
    const int kk = t >> 5, quad = (t >> 3) & 3, b = t & 7;
    const int flane = (k & 15) + (quad << 4);
    const int g = k >> 4;
    bws2[(size_t)(g * 2 + (kk >> 1)) * 1024 + flane * 16 + (kk & 1) * 8 + b] =
        (unsigned char)(pk_fp8<false>(q, q, 0u) & 0xFFu);
    if (t == 0) cnorm[k] = n;
}

// ---- Main: 8 waves x own tile; half-B LDS-resident; 3 barriers total ----
__global__ __launch_bounds__(512, 1) void cluster_main(
    const float* __restrict__ feats,        // [N][128] fp32
    const unsigned char* __restrict__ bws2, // frag-linear fp8 centers, 128 KB
    const float* __restrict__ cnorm,        // [1024] fp32
    float* __restrict__ wsum) {

    extern __shared__ unsigned char Bs[];    // 65536 B: current half of B
    __shared__ float nf_w[8][32];
    __shared__ float bm_w[8][32];

    const int tid  = threadIdx.x;            // 0..511, 8 waves
    const int lane = tid & 63;
    const int w    = tid >> 6;
    const int m16  = lane & 15;
    const int quad = lane >> 4;              // 0..3

    const int gw   = blockIdx.x * 8 + w;     // global wave id = tile id
    const int row0 = gw * 32;

    // ---- A fragments direct from global (R15/R18-verified) + row sumsq ----
    long long afr[2][4];
    float sq[2];
    #pragma unroll
    for (int i2 = 0; i2 < 2; ++i2) {
        const float* rp = feats + (size_t)(row0 + i2 * 16 + m16) * D + quad * 8;
        float a = 0.0f;
        #pragma unroll
        for (int kk = 0; kk < 4; ++kk) {
            float4 u = *(const float4*)(rp + kk * 32);
            float4 v = *(const float4*)(rp + kk * 32 + 4);
            unsigned int lo = pk_fp8<true>(u.z, u.w, pk_fp8<false>(u.x, u.y, 0u));
            unsigned int hi = pk_fp8<true>(v.z, v.w, pk_fp8<false>(v.x, v.y, 0u));
            afr[i2][kk] = (long long)(((unsigned long long)hi << 32) | (unsigned long long)lo);
            a += u.x*u.x + u.y*u.y + u.z*u.z + u.w*u.w;
            a += v.x*v.x + v.y*v.y + v.z*v.z + v.w*v.w;
        }
        sq[i2] = a;
    }
    #pragma unroll
    for (int i2 = 0; i2 < 2; ++i2) {         // reduce over quads (cols)
        sq[i2] += __shfl_xor(sq[i2], 16);
        sq[i2] += __shfl_xor(sq[i2], 32);
    }
    if (quad == 0) {
        #pragma unroll
        for (int i2 = 0; i2 < 2; ++i2) nf_w[w][i2 * 16 + m16] = sq[i2];
    }

    float best[8];                           // keyed floats, slot = i2*4 + r
    #pragma unroll
    for (int s = 0; s < 8; ++s) best[s] = -3.0e38f;

    const unsigned char* bb = Bs + lane * 16;

    auto loadB = [&](int g2, llx2& x0, llx2& x1, llx2& x2, llx2& x3) {
        const unsigned char* p = bb + (size_t)g2 * 4096;
        x0 = *(const llx2*)(p);              // group 2g2,   kk0/kk1
        x1 = *(const llx2*)(p + 1024);       // group 2g2,   kk2/kk3
        x2 = *(const llx2*)(p + 2048);       // group 2g2+1, kk0/kk1
        x3 = *(const llx2*)(p + 3072);       // group 2g2+1, kk2/kk3
    };
    auto stepB = [&](int gbase, int g2, llx2 x0, llx2 x1, llx2 x2, llx2 x3) {
        long long br0[4] = { x0[0], x0[1], x1[0], x1[1] };
        long long br1[4] = { x2[0], x2[1], x3[0], x3[1] };
        floatx4 a00 = (floatx4){0.f,0.f,0.f,0.f};
        floatx4 a01 = (floatx4){0.f,0.f,0.f,0.f};
        floatx4 a10 = (floatx4){0.f,0.f,0.f,0.f};
        floatx4 a11 = (floatx4){0.f,0.f,0.f,0.f};
        #pragma unroll
        for (int kk = 0; kk < 4; ++kk) {
            a00 = __builtin_amdgcn_mfma_f32_16x16x32_fp8_fp8(afr[0][kk], br0[kk], a00, 0, 0, 0);
            a01 = __builtin_amdgcn_mfma_f32_16x16x32_fp8_fp8(afr[0][kk], br1[kk], a01, 0, 0, 0);
            a10 = __builtin_amdgcn_mfma_f32_16x16x32_fp8_fp8(afr[1][kk], br0[kk], a10, 0, 0, 0);
            a11 = __builtin_amdgcn_mfma_f32_16x16x32_fp8_fp8(afr[1][kk], br1[kk], a11, 0, 0, 0);
        }
        const unsigned int inv0 = 1023u - (unsigned)(gbase + g2 * 32 + m16);
        const unsigned int inv1 = inv0 - 16u;
        #pragma unroll
        for (int r = 0; r < 4; ++r) {
            best[r]     = fmaxf(best[r],
                           fmaxf(key_pack(a00[r], inv0), key_pack(a01[r], inv1)));
            best[4 + r] = fmaxf(best[4 + r],
                           fmaxf(key_pack(a10[r], inv0), key_pack(a11[r], inv1)));
        }
    };

    #pragma unroll 1
    for (int half = 0; half < 2; ++half) {
        if (half) __syncthreads();           // all reads of half 0 done
        // ---- Stage half-B: linear 64 KB copy, 8 iters x 512 thr x 16 B ----
        const unsigned char* src = bws2 + (size_t)half * 65536;
        #pragma unroll 4
        for (int i = 0; i < 8; ++i) {
            uint4 v = *(const uint4*)(src + (size_t)i * 8192 + tid * 16);
            *(uint4*)&Bs[i * 8192 + tid * 16] = v;
        }
        __syncthreads();                     // Bs staged (+ nf_w on half 0)

        // ---- sweep 512 centers: 16 pair-groups, depth-1 LDS pipeline ----
        const int gbase = half * 512;
        llx2 xa0, xa1, xa2, xa3, yb0, yb1, yb2, yb3;
        loadB(0, xa0, xa1, xa2, xa3);
        #pragma unroll 1
        for (int it2 = 0; it2 < 8; ++it2) {
            loadB(2 * it2 + 1, yb0, yb1, yb2, yb3);
            stepB(gbase, 2 * it2,     xa0, xa1, xa2, xa3);
            if (it2 < 7)
                loadB(2 * it2 + 2, xa0, xa1, xa2, xa3);
            stepB(gbase, 2 * it2 + 1, yb0, yb1, yb2, yb3);
        }
    }

    // cross-m16 butterfly: per (quad,i2,r) max over all 1024 centers
    #pragma unroll
    for (int mask = 1; mask <= 8; mask <<= 1)
        #pragma unroll
        for (int s = 0; s < 8; ++s)
            best[s] = fmaxf(best[s], __shfl_xor(best[s], mask));

    if (m16 == 0) {
        #pragma unroll
        for (int s = 0; s < 8; ++s) {
            int row = (s >> 2) * 16 + quad * 4 + (s & 3);
            bm_w[w][row] = best[s];
        }
    }
    asm volatile("s_waitcnt lgkmcnt(0)" ::: "memory");  // bm_w wave-visible

    // ---- decode + loss, 32 rows on 32 lanes; wave reduce; one store ----
    float lsum = 0.0f;
    if (lane < 32) {
        const int row = lane;
        unsigned int ub = __builtin_bit_cast(unsigned int, bm_w[w][row]);
        int   ka = 1023 - (int)(ub & 1023u);
        float d  = __builtin_bit_cast(float, (ub & 0xFFFFFC00u) | 0x200u);
        float nf = fmaxf(sqrtf(nf_w[w][row]), 1e-12f);
        float na = cnorm[ka];
        lsum = 1.0f - 2.0f * d * na / nf + na * na;
    }
    #pragma unroll
    for (int m = 1; m <= 32; m <<= 1) lsum += __shfl_xor(lsum, m);
    if (lane == 0) wsum[gw] = lsum;
}

// ---- Final: sum 4096 per-wave partials -> out[0] ----
__global__ void reduce_out(const float* __restrict__ wsum,
                           float* __restrict__ out, int nW, float invN) {
    float s = 0.0f;
    for (int i = threadIdx.x; i < (nW >> 2); i += 256) {
        float4 v = ((const float4*)wsum)[i];
        s += (v.x + v.y) + (v.z + v.w);
    }
    #pragma unroll
    for (int m = 1; m <= 32; m <<= 1) s += __shfl_xor(s, m);
    __shared__ float ws4[4];
    if ((threadIdx.x & 63) == 0) ws4[threadIdx.x >> 6] = s;
    __syncthreads();
    if (threadIdx.x == 0)
        out[0] = ((ws4[0] + ws4[1]) + (ws4[2] + ws4[3])) * invN;
}

extern "C" void kernel_launch(void* const* d_in, const int* in_sizes, int n_in,
                              void* d_out, int out_size, void* d_ws, size_t ws_size,
                              hipStream_t stream) {
    const float* feats   = (const float*)d_in[0];
    const float* centers = (const float*)d_in[1];
    const int N = in_sizes[0] / D;   // 131072
    const int K = in_sizes[1] / D;   // 1024

    unsigned char* bws2 = (unsigned char*)d_ws;                    // 128 KB
    float* cnorm = (float*)((char*)d_ws + (size_t)K * D);          // 4 KB
    float* wsum  = (float*)((char*)d_ws + (size_t)K * D + 4096);   // 16 KB
    float* out = (float*)d_out;

    const int smem = 65536;                  // half-B (~67.5 KB w/ static)
    (void)hipFuncSetAttribute((const void*)cluster_main,
                              hipFuncAttributeMaxDynamicSharedMemorySize, smem);

    prep_centers<<<K, D, 0, stream>>>(centers, bws2, cnorm);

    const int grid = (N / 32) / 8;           // 512 blocks x 8 waves = 4096 tiles
    cluster_main<<<grid, 512, smem, stream>>>(feats, bws2, cnorm, wsum);

    reduce_out<<<1, 256, 0, stream>>>(wsum, out, grid * 8, 1.0f / (float)N);
}